// Round 3
// baseline (980.924 us; speedup 1.0000x reference)
//
#include <hip/hip_runtime.h>

#define N_NODES 50000
#define N_EDGES 1600000
#define IN_F 256
#define H1_F 128
#define H2_F 64
#define OUT_F 2
#define BN_EPS 1e-5f

#define NBUK 782          // ceil(50000/64) buckets of 64 nodes
#define BCAP 3584         // LDS edge capacity per bucket (avg 2048, 34-sigma margin)

// ---------------------------------------------------------------- bf16 helpers
__device__ __forceinline__ unsigned short f2b(float f) {
    union { float f; unsigned u; } v; v.f = f;
    unsigned r = (v.u + 0x7FFFu + ((v.u >> 16) & 1u)) >> 16;
    return (unsigned short)r;
}
__device__ __forceinline__ float b2f(unsigned short b) {
    union { unsigned u; float f; } v; v.u = ((unsigned)b) << 16;
    return v.f;
}
// accumulate two packed bf16 (low = feature f, high = feature f+1)
__device__ __forceinline__ void add2(float& a0, float& a1, unsigned u) {
    union { unsigned u; float f; } lo, hi;
    lo.u = u << 16;
    hi.u = u & 0xFFFF0000u;
    a0 += lo.f; a1 += hi.f;
}

// ---------------------------------------------------------------- bucket histogram (dst>>6)
__global__ void hist_kernel(const int* __restrict__ dst, int* __restrict__ bcnt) {
    int i = blockIdx.x * blockDim.x + threadIdx.x;   // one int4 (4 edges) per thread
    if (i < N_EDGES / 4) {
        int4 d = ((const int4*)dst)[i];
        atomicAdd(&bcnt[d.x >> 6], 1);
        atomicAdd(&bcnt[d.y >> 6], 1);
        atomicAdd(&bcnt[d.z >> 6], 1);
        atomicAdd(&bcnt[d.w >> 6], 1);
    }
}

// ---------------------------------------------------------------- bucket scan (single block)
__global__ void bscan_kernel(const int* __restrict__ bcnt, int* __restrict__ boff,
                             int* __restrict__ bcur, int* __restrict__ rowptr) {
    __shared__ int tmp[1024];
    int t = threadIdx.x;
    int v = (t < NBUK) ? bcnt[t] : 0;
    tmp[t] = v;
    __syncthreads();
    for (int off = 1; off < 1024; off <<= 1) {
        int a = (t >= off) ? tmp[t - off] : 0;
        __syncthreads();
        tmp[t] += a;
        __syncthreads();
    }
    if (t < NBUK) {
        int e = tmp[t] - v;   // exclusive
        boff[t] = e;
        bcur[t] = e;
    }
    if (t == 0) {
        boff[NBUK] = N_EDGES;
        rowptr[N_NODES] = N_EDGES;
    }
}

// ---------------------------------------------------------------- scatter edges to bucket-sorted order (packed 4B)
__global__ void bscatter_kernel(const int* __restrict__ src, const int* __restrict__ dst,
                                int* __restrict__ bcur, unsigned* __restrict__ bedges) {
    int e = blockIdx.x * blockDim.x + threadIdx.x;
    if (e < N_EDGES) {
        int s = src[e];
        int d = dst[e];
        int slot = atomicAdd(&bcur[d >> 6], 1);
        bedges[slot] = (unsigned)s | ((unsigned)d << 16);
    }
}

// ---------------------------------------------------------------- per-bucket CSR build (rowptr, dinv, perm) in LDS
__launch_bounds__(256)
__global__ void build_kernel(const unsigned* __restrict__ bedges, const int* __restrict__ boff,
                             unsigned short* __restrict__ perm, int* __restrict__ rowptr,
                             float* __restrict__ dinv) {
    __shared__ unsigned e_lds[BCAP];
    __shared__ unsigned short p_lds[BCAP];
    __shared__ int ncnt[64], ncur[64];

    const int b = blockIdx.x;
    const int t = threadIdx.x;
    const int start = boff[b];
    const int end   = boff[b + 1];
    const int cnt   = end - start;
    const bool fits = (cnt <= BCAP);

    if (t < 64) ncnt[t] = 0;
    __syncthreads();

    for (int i = t; i < cnt; i += 256) {
        unsigned e = bedges[start + i];
        if (fits) e_lds[i] = e;
        atomicAdd(&ncnt[(e >> 16) & 63], 1);
    }
    __syncthreads();

    if (t == 0) {   // tiny serial exclusive scan over 64 node counts
        int a = 0;
        for (int i = 0; i < 64; ++i) { ncur[i] = a; a += ncnt[i]; }
    }
    __syncthreads();

    if (t < 64) {
        int node = b * 64 + t;
        if (node < N_NODES) {
            rowptr[node] = start + ncur[t];
            dinv[node]   = rsqrtf((float)ncnt[t] + 1.0f);   // +1 self loop
        }
    }
    __syncthreads();

    for (int i = t; i < cnt; i += 256) {
        unsigned e = fits ? e_lds[i] : bedges[start + i];
        int slot = atomicAdd(&ncur[(e >> 16) & 63], 1);
        unsigned short s = (unsigned short)(e & 0xFFFFu);
        if (fits) p_lds[slot] = s;
        else      perm[start + slot] = s;
    }
    if (fits) {
        __syncthreads();
        for (int i = t; i < cnt; i += 256) perm[start + i] = p_lds[i];   // coalesced
    }
}

// ---------------------------------------------------------------- GEMM  C[r,c] = bf16( (A@B)[r,c] * dscale[r] )
// A: fp32 or bf16 (row-major MxK), B: fp32 (KxBN), C: bf16
template <typename AT, int BN, int TN>
__launch_bounds__(256)
__global__ void gemm_kernel(const AT* __restrict__ A, const float* __restrict__ B,
                            const float* __restrict__ dscale, unsigned short* __restrict__ C,
                            int M, int K) {
    constexpr int BM = 64;
    constexpr int BK = 16;
    __shared__ float As[BM][BK + 4];
    __shared__ float Bs[BK][BN];

    const int tid  = threadIdx.x;
    const int row0 = blockIdx.x * BM;
    const int tcol = tid & 15;
    const int trow = tid >> 4;

    float acc[4][TN];
#pragma unroll
    for (int i = 0; i < 4; ++i)
#pragma unroll
        for (int j = 0; j < TN; ++j) acc[i][j] = 0.f;

    const int arow = tid >> 2;
    const int acol = (tid & 3) << 2;
    int ar = row0 + arow;
    if (ar >= M) ar = M - 1;

    for (int k0 = 0; k0 < K; k0 += BK) {
        if constexpr (sizeof(AT) == 4) {
            float4 av = *(const float4*)((const float*)A + (size_t)ar * K + k0 + acol);
            *(float4*)(&As[arow][acol]) = av;
        } else {
            ushort4 av = *(const ushort4*)((const unsigned short*)A + (size_t)ar * K + k0 + acol);
            As[arow][acol + 0] = b2f(av.x);
            As[arow][acol + 1] = b2f(av.y);
            As[arow][acol + 2] = b2f(av.z);
            As[arow][acol + 3] = b2f(av.w);
        }
        constexpr int B4 = BN / 4;
#pragma unroll
        for (int l = tid; l < BK * B4; l += 256) {
            int brow = l / B4;
            int bcol = (l % B4) << 2;
            *(float4*)(&Bs[brow][bcol]) =
                *(const float4*)(B + (size_t)(k0 + brow) * BN + bcol);
        }
        __syncthreads();
#pragma unroll
        for (int kk = 0; kk < BK; ++kk) {
            float a[4];
#pragma unroll
            for (int i = 0; i < 4; ++i) a[i] = As[trow * 4 + i][kk];
            float b[TN];
#pragma unroll
            for (int j = 0; j < TN; ++j) b[j] = Bs[kk][tcol * TN + j];
#pragma unroll
            for (int i = 0; i < 4; ++i)
#pragma unroll
                for (int j = 0; j < TN; ++j) acc[i][j] += a[i] * b[j];
        }
        __syncthreads();
    }
#pragma unroll
    for (int i = 0; i < 4; ++i) {
        int r = row0 + trow * 4 + i;
        if (r < M) {
            float ds = dscale[r];
#pragma unroll
            for (int j = 0; j < TN; j += 4) {
                ushort4 o;
                o.x = f2b(acc[i][j + 0] * ds);
                o.y = f2b(acc[i][j + 1] * ds);
                o.z = f2b(acc[i][j + 2] * ds);
                o.w = f2b(acc[i][j + 3] * ds);
                *(ushort4*)(C + (size_t)r * BN + tcol * TN + j) = o;
            }
        }
    }
}

// ---------------------------------------------------------------- fused aggregation (bf16 gather, fp32 accum)
//   y[d][f] = relu( (dinv[d]*(xw_s[d][f] + sum_neighbors)) * sc[f] + sh[f] )
//   one wave per node; halves of the wave take alternating edges; FPQ feats/lane
template <int HF, bool FINAL>
__launch_bounds__(256)
__global__ void agg_kernel(const int* __restrict__ rowptr, const unsigned short* __restrict__ perm,
                           const unsigned short* __restrict__ xwb, const float* __restrict__ dinv,
                           const float* __restrict__ bias, const float* __restrict__ g,
                           const float* __restrict__ be, const float* __restrict__ m,
                           const float* __restrict__ v, const float* __restrict__ Wl,
                           const float* __restrict__ bl, void* __restrict__ outp) {
    constexpr int FPQ = HF / 32;   // 4 for HF=128, 2 for HF=64
    const int wid = (blockIdx.x * blockDim.x + threadIdx.x) >> 6;
    if (wid >= N_NODES) return;
    const int lane = threadIdx.x & 63;
    const int half = lane >> 5;
    const int l5   = lane & 31;
    const int f0   = l5 * FPQ;
    const int d    = wid;

    float acc[FPQ];
#pragma unroll
    for (int q = 0; q < FPQ; ++q) acc[q] = 0.f;

    // self term (lower half only; halves are summed at the end)
    if (half == 0) {
        if constexpr (FPQ == 4) {
            uint2 t = *(const uint2*)(xwb + (size_t)d * HF + f0);
            add2(acc[0], acc[1], t.x);
            add2(acc[2], acc[3], t.y);
        } else {
            unsigned t = *(const unsigned*)(xwb + (size_t)d * HF + f0);
            add2(acc[0], acc[1], t);
        }
    }

    const int start = rowptr[d];
    const int end   = rowptr[d + 1];
    for (int base = start; base < end; base += 64) {
        int pidx = base + lane;
        int pv = perm[pidx < end ? pidx : end - 1];
        int ne = end - base;
        if (ne > 64) ne = 64;
        if (ne == 64) {
#pragma unroll
            for (int j = 0; j < 64; j += 2) {
                int s = __shfl(pv, j + half);
                if constexpr (FPQ == 4) {
                    uint2 t = *(const uint2*)(xwb + (size_t)s * HF + f0);
                    add2(acc[0], acc[1], t.x);
                    add2(acc[2], acc[3], t.y);
                } else {
                    unsigned t = *(const unsigned*)(xwb + (size_t)s * HF + f0);
                    add2(acc[0], acc[1], t);
                }
            }
        } else {
            for (int j = 0; j < ne; j += 2) {
                int s = __shfl(pv, j + half);     // all lanes execute the shfl
                if (j + half < ne) {
                    if constexpr (FPQ == 4) {
                        uint2 t = *(const uint2*)(xwb + (size_t)s * HF + f0);
                        add2(acc[0], acc[1], t.x);
                        add2(acc[2], acc[3], t.y);
                    } else {
                        unsigned t = *(const unsigned*)(xwb + (size_t)s * HF + f0);
                        add2(acc[0], acc[1], t);
                    }
                }
            }
        }
    }

    // combine the two half-wave partial sums
#pragma unroll
    for (int q = 0; q < FPQ; ++q) acc[q] += __shfl_xor(acc[q], 32);

    const float dv = dinv[d];
    float y[FPQ];
#pragma unroll
    for (int q = 0; q < FPQ; ++q) {
        int f = f0 + q;
        float s  = g[f] * rsqrtf(v[f] + BN_EPS);
        float sh = (bias[f] - m[f]) * s + be[f];
        y[q] = fmaxf(acc[q] * dv * s + sh, 0.f);
    }

    if constexpr (!FINAL) {
        if (half == 0) {
            if constexpr (FPQ == 4) {
                ushort4 o;
                o.x = f2b(y[0]); o.y = f2b(y[1]); o.z = f2b(y[2]); o.w = f2b(y[3]);
                *(ushort4*)((unsigned short*)outp + (size_t)d * HF + f0) = o;
            }
        }
    } else {
        // fused 64->2 linear; h2 never materialized
        float p0 = y[0] * Wl[f0 * 2 + 0] + y[1] * Wl[(f0 + 1) * 2 + 0];
        float p1 = y[0] * Wl[f0 * 2 + 1] + y[1] * Wl[(f0 + 1) * 2 + 1];
#pragma unroll
        for (int off = 16; off > 0; off >>= 1) {
            p0 += __shfl_xor(p0, off);
            p1 += __shfl_xor(p1, off);
        }
        if (lane == 0) {
            float* o = (float*)outp;
            o[(size_t)d * 2 + 0] = p0 + bl[0];
            o[(size_t)d * 2 + 1] = p1 + bl[1];
        }
    }
}

// ---------------------------------------------------------------- launcher
extern "C" void kernel_launch(void* const* d_in, const int* in_sizes, int n_in,
                              void* d_out, int out_size, void* d_ws, size_t ws_size,
                              hipStream_t stream) {
    const float* x   = (const float*)d_in[0];
    const int*   ei  = (const int*)d_in[1];
    const float* W1  = (const float*)d_in[2];
    const float* b1  = (const float*)d_in[3];
    const float* g1  = (const float*)d_in[4];
    const float* be1 = (const float*)d_in[5];
    const float* m1  = (const float*)d_in[6];
    const float* v1  = (const float*)d_in[7];
    const float* W2  = (const float*)d_in[8];
    const float* b2  = (const float*)d_in[9];
    const float* g2  = (const float*)d_in[10];
    const float* be2 = (const float*)d_in[11];
    const float* m2  = (const float*)d_in[12];
    const float* v2  = (const float*)d_in[13];
    const float* Wl  = (const float*)d_in[14];
    const float* bl  = (const float*)d_in[15];

    const int* src = ei;            // edge_index[0]
    const int* dst = ei + N_EDGES;  // edge_index[1]

    // workspace layout (4B units)
    int*            bcnt   = (int*)d_ws;                         // 1024
    int*            boff   = bcnt + 1024;                        // 1024 (NBUK+1 used)
    int*            bcur   = boff + 1024;                        // 1024
    int*            rowptr = bcur + 1024;                        // 50016 (N+1 used)
    float*          dinv   = (float*)(rowptr + 50016);           // 50016
    unsigned*       bedges = (unsigned*)(dinv + 50016);          // E
    unsigned short* perm   = (unsigned short*)(bedges + N_EDGES);     // E ushorts
    unsigned short* xwb    = perm + N_EDGES;                     // N*128 bf16 (layer2 reuses as N*64)
    unsigned short* h1b    = xwb + (size_t)N_NODES * H1_F;       // N*128 bf16

    hipMemsetAsync(bcnt, 0, 1024 * sizeof(int), stream);

    // ---- CSR build (bucketed) ----
    hist_kernel<<<(N_EDGES / 4 + 255) / 256, 256, 0, stream>>>(dst, bcnt);
    bscan_kernel<<<1, 1024, 0, stream>>>(bcnt, boff, bcur, rowptr);
    bscatter_kernel<<<(N_EDGES + 255) / 256, 256, 0, stream>>>(src, dst, bcur, bedges);
    build_kernel<<<NBUK, 256, 0, stream>>>(bedges, boff, perm, rowptr, dinv);

    // ---- layer 1 ----
    gemm_kernel<float, H1_F, 8><<<(N_NODES + 63) / 64, 256, 0, stream>>>(
        x, W1, dinv, xwb, N_NODES, IN_F);
    agg_kernel<H1_F, false><<<(N_NODES * 64) / 256, 256, 0, stream>>>(
        rowptr, perm, xwb, dinv, b1, g1, be1, m1, v1, nullptr, nullptr, h1b);

    // ---- layer 2 + final linear fused ----
    gemm_kernel<unsigned short, H2_F, 4><<<(N_NODES + 63) / 64, 256, 0, stream>>>(
        h1b, W2, dinv, xwb, N_NODES, H1_F);
    agg_kernel<H2_F, true><<<(N_NODES * 64) / 256, 256, 0, stream>>>(
        rowptr, perm, xwb, dinv, b2, g2, be2, m2, v2, Wl, bl, (float*)d_out);
}

// Round 4
// 267.339 us; speedup vs baseline: 3.6692x; 3.6692x over previous
//
#include <hip/hip_runtime.h>

#define N_NODES 50000
#define N_EDGES 1600000
#define IN_F 256
#define H1_F 128
#define H2_F 64
#define OUT_F 2
#define BN_EPS 1e-5f

#define NBUK 782          // ceil(50000/64) buckets of 64 nodes
#define BCAP 3584         // LDS edge capacity per bucket in build (avg 2048)
#define CHUNK 8192        // edges per chunk in the two-level counting sort
#define NCHUNK 196        // ceil(1600000/8192)

// ---------------------------------------------------------------- bf16 helpers
__device__ __forceinline__ unsigned short f2b(float f) {
    union { float f; unsigned u; } v; v.f = f;
    unsigned r = (v.u + 0x7FFFu + ((v.u >> 16) & 1u)) >> 16;
    return (unsigned short)r;
}
__device__ __forceinline__ float b2f(unsigned short b) {
    union { unsigned u; float f; } v; v.u = ((unsigned)b) << 16;
    return v.f;
}
// accumulate two packed bf16 (low = feature f, high = feature f+1)
__device__ __forceinline__ void add2(float& a0, float& a1, unsigned u) {
    union { unsigned u; float f; } lo, hi;
    lo.u = u << 16;
    hi.u = u & 0xFFFF0000u;
    a0 += lo.f; a1 += hi.f;
}

// ---------------------------------------------------------------- pass A: per-chunk bucket histogram (LDS, coalesced out)
__launch_bounds__(512)
__global__ void chist_kernel(const int* __restrict__ dst, int* __restrict__ h) {
    __shared__ int lh[NBUK];
    const int c = blockIdx.x;
    for (int i = threadIdx.x; i < NBUK; i += 512) lh[i] = 0;
    __syncthreads();
    const int e0 = c * CHUNK;
    const int e1 = min(e0 + CHUNK, N_EDGES);
    for (int e = e0 + threadIdx.x; e < e1; e += 512)
        atomicAdd(&lh[dst[e] >> 6], 1);
    __syncthreads();
    for (int i = threadIdx.x; i < NBUK; i += 512)
        h[c * NBUK + i] = lh[i];
}

// ---------------------------------------------------------------- pass B: bucket totals -> scan -> in-place (chunk,bucket) offsets
__global__ void bscan2_kernel(int* __restrict__ h, int* __restrict__ boff,
                              int* __restrict__ rowptr) {
    __shared__ int tmp[1024];
    const int t = threadIdx.x;
    int tot = 0;
    if (t < NBUK)
        for (int c = 0; c < NCHUNK; ++c) tot += h[c * NBUK + t];
    tmp[t] = tot;
    __syncthreads();
    for (int off = 1; off < 1024; off <<= 1) {
        int a = (t >= off) ? tmp[t - off] : 0;
        __syncthreads();
        tmp[t] += a;
        __syncthreads();
    }
    const int excl = tmp[t] - tot;
    if (t < NBUK) boff[t] = excl;
    if (t == 0) { boff[NBUK] = N_EDGES; rowptr[N_NODES] = N_EDGES; }
    if (t < NBUK) {
        int run = excl;
        for (int c = 0; c < NCHUNK; ++c) {
            int v = h[c * NBUK + t];
            h[c * NBUK + t] = run;   // exact global start of this (chunk,bucket) run
            run += v;
        }
    }
}

// ---------------------------------------------------------------- pass C: scatter to precomputed slots (LDS cursors only)
__launch_bounds__(512)
__global__ void cscatter_kernel(const int* __restrict__ src, const int* __restrict__ dst,
                                const int* __restrict__ h, unsigned* __restrict__ bedges) {
    __shared__ int cur[NBUK];
    const int c = blockIdx.x;
    for (int i = threadIdx.x; i < NBUK; i += 512) cur[i] = h[c * NBUK + i];
    __syncthreads();
    const int e0 = c * CHUNK;
    const int e1 = min(e0 + CHUNK, N_EDGES);
    for (int e = e0 + threadIdx.x; e < e1; e += 512) {
        int s = src[e];
        int d = dst[e];
        int slot = atomicAdd(&cur[d >> 6], 1);    // LDS returning atomic, depth ~10
        bedges[slot] = (unsigned)s | ((unsigned)d << 16);
    }
}

// ---------------------------------------------------------------- per-bucket CSR build (rowptr, dinv, perm) in LDS
__launch_bounds__(256)
__global__ void build_kernel(const unsigned* __restrict__ bedges, const int* __restrict__ boff,
                             unsigned short* __restrict__ perm, int* __restrict__ rowptr,
                             float* __restrict__ dinv) {
    __shared__ unsigned e_lds[BCAP];
    __shared__ unsigned short p_lds[BCAP];
    __shared__ int ncnt[64], ncur[64];

    const int b = blockIdx.x;
    const int t = threadIdx.x;
    const int start = boff[b];
    const int end   = boff[b + 1];
    const int cnt   = end - start;
    const bool fits = (cnt <= BCAP);

    if (t < 64) ncnt[t] = 0;
    __syncthreads();

    for (int i = t; i < cnt; i += 256) {
        unsigned e = bedges[start + i];
        if (fits) e_lds[i] = e;
        atomicAdd(&ncnt[(e >> 16) & 63], 1);
    }
    __syncthreads();

    if (t == 0) {
        int a = 0;
        for (int i = 0; i < 64; ++i) { ncur[i] = a; a += ncnt[i]; }
    }
    __syncthreads();

    if (t < 64) {
        int node = b * 64 + t;
        if (node < N_NODES) {
            rowptr[node] = start + ncur[t];
            dinv[node]   = rsqrtf((float)ncnt[t] + 1.0f);   // +1 self loop
        }
    }
    __syncthreads();

    for (int i = t; i < cnt; i += 256) {
        unsigned e = fits ? e_lds[i] : bedges[start + i];
        int slot = atomicAdd(&ncur[(e >> 16) & 63], 1);
        unsigned short s = (unsigned short)(e & 0xFFFFu);
        if (fits) p_lds[slot] = s;
        else      perm[start + slot] = s;
    }
    if (fits) {
        __syncthreads();
        for (int i = t; i < cnt; i += 256) perm[start + i] = p_lds[i];   // coalesced
    }
}

// ---------------------------------------------------------------- GEMM  C[r,c] = bf16( (A@B)[r,c] * dscale[r] )
template <typename AT, int BN, int TN>
__launch_bounds__(256)
__global__ void gemm_kernel(const AT* __restrict__ A, const float* __restrict__ B,
                            const float* __restrict__ dscale, unsigned short* __restrict__ C,
                            int M, int K) {
    constexpr int BM = 64;
    constexpr int BK = 16;
    __shared__ float As[BM][BK + 4];
    __shared__ float Bs[BK][BN];

    const int tid  = threadIdx.x;
    const int row0 = blockIdx.x * BM;
    const int tcol = tid & 15;
    const int trow = tid >> 4;

    float acc[4][TN];
#pragma unroll
    for (int i = 0; i < 4; ++i)
#pragma unroll
        for (int j = 0; j < TN; ++j) acc[i][j] = 0.f;

    const int arow = tid >> 2;
    const int acol = (tid & 3) << 2;
    int ar = row0 + arow;
    if (ar >= M) ar = M - 1;

    for (int k0 = 0; k0 < K; k0 += BK) {
        if constexpr (sizeof(AT) == 4) {
            float4 av = *(const float4*)((const float*)A + (size_t)ar * K + k0 + acol);
            *(float4*)(&As[arow][acol]) = av;
        } else {
            ushort4 av = *(const ushort4*)((const unsigned short*)A + (size_t)ar * K + k0 + acol);
            As[arow][acol + 0] = b2f(av.x);
            As[arow][acol + 1] = b2f(av.y);
            As[arow][acol + 2] = b2f(av.z);
            As[arow][acol + 3] = b2f(av.w);
        }
        constexpr int B4 = BN / 4;
#pragma unroll
        for (int l = tid; l < BK * B4; l += 256) {
            int brow = l / B4;
            int bcol = (l % B4) << 2;
            *(float4*)(&Bs[brow][bcol]) =
                *(const float4*)(B + (size_t)(k0 + brow) * BN + bcol);
        }
        __syncthreads();
#pragma unroll
        for (int kk = 0; kk < BK; ++kk) {
            float a[4];
#pragma unroll
            for (int i = 0; i < 4; ++i) a[i] = As[trow * 4 + i][kk];
            float b[TN];
#pragma unroll
            for (int j = 0; j < TN; ++j) b[j] = Bs[kk][tcol * TN + j];
#pragma unroll
            for (int i = 0; i < 4; ++i)
#pragma unroll
                for (int j = 0; j < TN; ++j) acc[i][j] += a[i] * b[j];
        }
        __syncthreads();
    }
#pragma unroll
    for (int i = 0; i < 4; ++i) {
        int r = row0 + trow * 4 + i;
        if (r < M) {
            float ds = dscale[r];
#pragma unroll
            for (int j = 0; j < TN; j += 4) {
                ushort4 o;
                o.x = f2b(acc[i][j + 0] * ds);
                o.y = f2b(acc[i][j + 1] * ds);
                o.z = f2b(acc[i][j + 2] * ds);
                o.w = f2b(acc[i][j + 3] * ds);
                *(ushort4*)(C + (size_t)r * BN + tcol * TN + j) = o;
            }
        }
    }
}

// ---------------------------------------------------------------- fused aggregation (bf16 gather, fp32 accum)
template <int HF, bool FINAL>
__launch_bounds__(256)
__global__ void agg_kernel(const int* __restrict__ rowptr, const unsigned short* __restrict__ perm,
                           const unsigned short* __restrict__ xwb, const float* __restrict__ dinv,
                           const float* __restrict__ bias, const float* __restrict__ g,
                           const float* __restrict__ be, const float* __restrict__ m,
                           const float* __restrict__ v, const float* __restrict__ Wl,
                           const float* __restrict__ bl, void* __restrict__ outp) {
    constexpr int FPQ = HF / 32;   // 4 for HF=128, 2 for HF=64
    const int wid = (blockIdx.x * blockDim.x + threadIdx.x) >> 6;
    if (wid >= N_NODES) return;
    const int lane = threadIdx.x & 63;
    const int half = lane >> 5;
    const int l5   = lane & 31;
    const int f0   = l5 * FPQ;
    const int d    = wid;

    float acc[FPQ];
#pragma unroll
    for (int q = 0; q < FPQ; ++q) acc[q] = 0.f;

    if (half == 0) {
        if constexpr (FPQ == 4) {
            uint2 t = *(const uint2*)(xwb + (size_t)d * HF + f0);
            add2(acc[0], acc[1], t.x);
            add2(acc[2], acc[3], t.y);
        } else {
            unsigned t = *(const unsigned*)(xwb + (size_t)d * HF + f0);
            add2(acc[0], acc[1], t);
        }
    }

    const int start = rowptr[d];
    const int end   = rowptr[d + 1];
    for (int base = start; base < end; base += 64) {
        int pidx = base + lane;
        int pv = perm[pidx < end ? pidx : end - 1];
        int ne = end - base;
        if (ne > 64) ne = 64;
        if (ne == 64) {
#pragma unroll
            for (int j = 0; j < 64; j += 2) {
                int s = __shfl(pv, j + half);
                if constexpr (FPQ == 4) {
                    uint2 t = *(const uint2*)(xwb + (size_t)s * HF + f0);
                    add2(acc[0], acc[1], t.x);
                    add2(acc[2], acc[3], t.y);
                } else {
                    unsigned t = *(const unsigned*)(xwb + (size_t)s * HF + f0);
                    add2(acc[0], acc[1], t);
                }
            }
        } else {
            for (int j = 0; j < ne; j += 2) {
                int s = __shfl(pv, j + half);
                if (j + half < ne) {
                    if constexpr (FPQ == 4) {
                        uint2 t = *(const uint2*)(xwb + (size_t)s * HF + f0);
                        add2(acc[0], acc[1], t.x);
                        add2(acc[2], acc[3], t.y);
                    } else {
                        unsigned t = *(const unsigned*)(xwb + (size_t)s * HF + f0);
                        add2(acc[0], acc[1], t);
                    }
                }
            }
        }
    }

#pragma unroll
    for (int q = 0; q < FPQ; ++q) acc[q] += __shfl_xor(acc[q], 32);

    const float dv = dinv[d];
    float y[FPQ];
#pragma unroll
    for (int q = 0; q < FPQ; ++q) {
        int f = f0 + q;
        float s  = g[f] * rsqrtf(v[f] + BN_EPS);
        float sh = (bias[f] - m[f]) * s + be[f];
        y[q] = fmaxf(acc[q] * dv * s + sh, 0.f);
    }

    if constexpr (!FINAL) {
        if (half == 0) {
            if constexpr (FPQ == 4) {
                ushort4 o;
                o.x = f2b(y[0]); o.y = f2b(y[1]); o.z = f2b(y[2]); o.w = f2b(y[3]);
                *(ushort4*)((unsigned short*)outp + (size_t)d * HF + f0) = o;
            }
        }
    } else {
        float p0 = y[0] * Wl[f0 * 2 + 0] + y[1] * Wl[(f0 + 1) * 2 + 0];
        float p1 = y[0] * Wl[f0 * 2 + 1] + y[1] * Wl[(f0 + 1) * 2 + 1];
#pragma unroll
        for (int off = 16; off > 0; off >>= 1) {
            p0 += __shfl_xor(p0, off);
            p1 += __shfl_xor(p1, off);
        }
        if (lane == 0) {
            float* o = (float*)outp;
            o[(size_t)d * 2 + 0] = p0 + bl[0];
            o[(size_t)d * 2 + 1] = p1 + bl[1];
        }
    }
}

// ---------------------------------------------------------------- launcher
extern "C" void kernel_launch(void* const* d_in, const int* in_sizes, int n_in,
                              void* d_out, int out_size, void* d_ws, size_t ws_size,
                              hipStream_t stream) {
    const float* x   = (const float*)d_in[0];
    const int*   ei  = (const int*)d_in[1];
    const float* W1  = (const float*)d_in[2];
    const float* b1  = (const float*)d_in[3];
    const float* g1  = (const float*)d_in[4];
    const float* be1 = (const float*)d_in[5];
    const float* m1  = (const float*)d_in[6];
    const float* v1  = (const float*)d_in[7];
    const float* W2  = (const float*)d_in[8];
    const float* b2  = (const float*)d_in[9];
    const float* g2  = (const float*)d_in[10];
    const float* be2 = (const float*)d_in[11];
    const float* m2  = (const float*)d_in[12];
    const float* v2  = (const float*)d_in[13];
    const float* Wl  = (const float*)d_in[14];
    const float* bl  = (const float*)d_in[15];

    const int* src = ei;            // edge_index[0]
    const int* dst = ei + N_EDGES;  // edge_index[1]

    // workspace layout (4B units)
    int*            h      = (int*)d_ws;                          // NCHUNK*NBUK = 153272
    int*            boff   = h + NCHUNK * NBUK;                   // NBUK+1 (pad to 1024)
    int*            rowptr = boff + 1024;                         // N+1 (pad 50016)
    float*          dinv   = (float*)(rowptr + 50016);            // N (pad 50016)
    unsigned*       bedges = (unsigned*)(dinv + 50016);           // E
    unsigned short* perm   = (unsigned short*)(bedges + N_EDGES); // E ushorts
    unsigned short* xwb    = perm + N_EDGES;                      // N*128 bf16 (layer2 reuse N*64)
    unsigned short* h1b    = xwb + (size_t)N_NODES * H1_F;        // N*128 bf16

    // ---- CSR build: zero global returning atomics, fully deterministic ----
    chist_kernel<<<NCHUNK, 512, 0, stream>>>(dst, h);
    bscan2_kernel<<<1, 1024, 0, stream>>>(h, boff, rowptr);
    cscatter_kernel<<<NCHUNK, 512, 0, stream>>>(src, dst, h, bedges);
    build_kernel<<<NBUK, 256, 0, stream>>>(bedges, boff, perm, rowptr, dinv);

    // ---- layer 1 ----
    gemm_kernel<float, H1_F, 8><<<(N_NODES + 63) / 64, 256, 0, stream>>>(
        x, W1, dinv, xwb, N_NODES, IN_F);
    agg_kernel<H1_F, false><<<(N_NODES * 64) / 256, 256, 0, stream>>>(
        rowptr, perm, xwb, dinv, b1, g1, be1, m1, v1, nullptr, nullptr, h1b);

    // ---- layer 2 + final linear fused ----
    gemm_kernel<unsigned short, H2_F, 4><<<(N_NODES + 63) / 64, 256, 0, stream>>>(
        h1b, W2, dinv, xwb, N_NODES, H1_F);
    agg_kernel<H2_F, true><<<(N_NODES * 64) / 256, 256, 0, stream>>>(
        rowptr, perm, xwb, dinv, b2, g2, be2, m2, v2, Wl, bl, (float*)d_out);
}

// Round 5
// 254.405 us; speedup vs baseline: 3.8558x; 1.0508x over previous
//
#include <hip/hip_runtime.h>

#define N_NODES 50000
#define N_EDGES 1600000
#define IN_F 256
#define H1_F 128
#define H2_F 64
#define OUT_F 2
#define BN_EPS 1e-5f

#define NBUK 782          // ceil(50000/64) buckets of 64 nodes
#define BCAP 3584         // LDS edge capacity per bucket in build (avg 2048)
#define CHUNK 8192        // edges per chunk in the two-level counting sort
#define NCHUNK 196        // ceil(1600000/8192)

typedef __attribute__((ext_vector_type(8))) short bf16x8;   // 8 bf16 in 4 VGPRs
typedef __attribute__((ext_vector_type(4))) float f32x4;

// ---------------------------------------------------------------- bf16 helpers
__device__ __forceinline__ unsigned short f2b(float f) {
    union { float f; unsigned u; } v; v.f = f;
    unsigned r = (v.u + 0x7FFFu + ((v.u >> 16) & 1u)) >> 16;
    return (unsigned short)r;
}
__device__ __forceinline__ float b2f(unsigned short b) {
    union { unsigned u; float f; } v; v.u = ((unsigned)b) << 16;
    return v.f;
}
__device__ __forceinline__ void add2(float& a0, float& a1, unsigned u) {
    union { unsigned u; float f; } lo, hi;
    lo.u = u << 16;
    hi.u = u & 0xFFFF0000u;
    a0 += lo.f; a1 += hi.f;
}

// ---------------------------------------------------------------- pass A: per-chunk bucket histogram
__launch_bounds__(512)
__global__ void chist_kernel(const int* __restrict__ dst, int* __restrict__ h) {
    __shared__ int lh[NBUK];
    const int c = blockIdx.x;
    for (int i = threadIdx.x; i < NBUK; i += 512) lh[i] = 0;
    __syncthreads();
    const int e0 = c * CHUNK;
    const int e1 = min(e0 + CHUNK, N_EDGES);
    for (int e = e0 + threadIdx.x; e < e1; e += 512)
        atomicAdd(&lh[dst[e] >> 6], 1);
    __syncthreads();
    for (int i = threadIdx.x; i < NBUK; i += 512)
        h[c * NBUK + i] = lh[i];
}

// ---------------------------------------------------------------- pass B: totals -> scan -> per-(chunk,bucket) offsets
__global__ void bscan2_kernel(int* __restrict__ h, int* __restrict__ boff,
                              int* __restrict__ rowptr) {
    __shared__ int tmp[1024];
    const int t = threadIdx.x;
    int tot = 0;
    if (t < NBUK)
        for (int c = 0; c < NCHUNK; ++c) tot += h[c * NBUK + t];
    tmp[t] = tot;
    __syncthreads();
    for (int off = 1; off < 1024; off <<= 1) {
        int a = (t >= off) ? tmp[t - off] : 0;
        __syncthreads();
        tmp[t] += a;
        __syncthreads();
    }
    const int excl = tmp[t] - tot;
    if (t < NBUK) boff[t] = excl;
    if (t == 0) { boff[NBUK] = N_EDGES; rowptr[N_NODES] = N_EDGES; }
    if (t < NBUK) {
        int run = excl;
        for (int c = 0; c < NCHUNK; ++c) {
            int v = h[c * NBUK + t];
            h[c * NBUK + t] = run;
            run += v;
        }
    }
}

// ---------------------------------------------------------------- pass C: scatter to precomputed slots (LDS cursors only)
__launch_bounds__(512)
__global__ void cscatter_kernel(const int* __restrict__ src, const int* __restrict__ dst,
                                const int* __restrict__ h, unsigned* __restrict__ bedges) {
    __shared__ int cur[NBUK];
    const int c = blockIdx.x;
    for (int i = threadIdx.x; i < NBUK; i += 512) cur[i] = h[c * NBUK + i];
    __syncthreads();
    const int e0 = c * CHUNK;
    const int e1 = min(e0 + CHUNK, N_EDGES);
    for (int e = e0 + threadIdx.x; e < e1; e += 512) {
        int s = src[e];
        int d = dst[e];
        int slot = atomicAdd(&cur[d >> 6], 1);
        bedges[slot] = (unsigned)s | ((unsigned)d << 16);
    }
}

// ---------------------------------------------------------------- per-bucket CSR build
__launch_bounds__(256)
__global__ void build_kernel(const unsigned* __restrict__ bedges, const int* __restrict__ boff,
                             unsigned short* __restrict__ perm, int* __restrict__ rowptr,
                             float* __restrict__ dinv) {
    __shared__ unsigned e_lds[BCAP];
    __shared__ unsigned short p_lds[BCAP];
    __shared__ int ncnt[64], ncur[64];

    const int b = blockIdx.x;
    const int t = threadIdx.x;
    const int start = boff[b];
    const int end   = boff[b + 1];
    const int cnt   = end - start;
    const bool fits = (cnt <= BCAP);

    if (t < 64) ncnt[t] = 0;
    __syncthreads();

    for (int i = t; i < cnt; i += 256) {
        unsigned e = bedges[start + i];
        if (fits) e_lds[i] = e;
        atomicAdd(&ncnt[(e >> 16) & 63], 1);
    }
    __syncthreads();

    if (t == 0) {
        int a = 0;
        for (int i = 0; i < 64; ++i) { ncur[i] = a; a += ncnt[i]; }
    }
    __syncthreads();

    if (t < 64) {
        int node = b * 64 + t;
        if (node < N_NODES) {
            rowptr[node] = start + ncur[t];
            dinv[node]   = rsqrtf((float)ncnt[t] + 1.0f);   // +1 self loop
        }
    }
    __syncthreads();

    for (int i = t; i < cnt; i += 256) {
        unsigned e = fits ? e_lds[i] : bedges[start + i];
        int slot = atomicAdd(&ncur[(e >> 16) & 63], 1);
        unsigned short s = (unsigned short)(e & 0xFFFFu);
        if (fits) p_lds[slot] = s;
        else      perm[start + slot] = s;
    }
    if (fits) {
        __syncthreads();
        for (int i = t; i < cnt; i += 256) perm[start + i] = p_lds[i];
    }
}

// ---------------------------------------------------------------- weight transpose+convert: WT[n][k] = bf16(W[k][n])
__global__ void wt_kernel(const float* __restrict__ W, unsigned short* __restrict__ WT,
                          int K, int N) {
    int i = blockIdx.x * blockDim.x + threadIdx.x;
    if (i < N * K) {
        int n = i / K, k = i % K;
        WT[i] = f2b(W[(size_t)k * N + n]);
    }
}

// ---------------------------------------------------------------- MFMA GEMM: C[r][n] = bf16( (A@B)[r][n] * dscale[r] )
// A: [M][K] fp32 or bf16; BT: [NF][K] bf16 (transposed weights); one wave per 16-row strip.
// Fragment layout (mfma_f32_16x16x32_bf16): A row=l&15, k=(l>>4)*8+e; B col=l&15, same k;
// C/D col=lane&15, row=(lane>>4)*4+reg  [m89-verified].
template <int KSTEPS, int NTILES, bool A_BF16>
__launch_bounds__(256)
__global__ void mfma_gemm_kernel(const void* __restrict__ Ap, const unsigned short* __restrict__ BT,
                                 const float* __restrict__ dscale, unsigned short* __restrict__ C,
                                 int M) {
    constexpr int K  = KSTEPS * 32;
    constexpr int NF = NTILES * 16;
    const int wave = threadIdx.x >> 6;
    const int lane = threadIdx.x & 63;
    const int r0   = (blockIdx.x * 4 + wave) * 16;
    const int m    = lane & 15;
    const int kb   = lane >> 4;          // 0..3

    int arow = r0 + m;
    if (arow >= M) arow = M - 1;         // clamp loads; stores guarded

    f32x4 acc[NTILES];
#pragma unroll
    for (int nt = 0; nt < NTILES; ++nt) acc[nt] = (f32x4)(0.f);

#pragma unroll
    for (int ks = 0; ks < KSTEPS; ++ks) {
        const int k0 = ks * 32 + kb * 8;
        bf16x8 a;
        if constexpr (A_BF16) {
            a = *(const bf16x8*)((const unsigned short*)Ap + (size_t)arow * K + k0);
        } else {
            const float* af = (const float*)Ap + (size_t)arow * K + k0;
            float4 lo = *(const float4*)af;
            float4 hi = *(const float4*)(af + 4);
            union { bf16x8 v; unsigned short u[8]; } pk;
            pk.u[0] = f2b(lo.x); pk.u[1] = f2b(lo.y); pk.u[2] = f2b(lo.z); pk.u[3] = f2b(lo.w);
            pk.u[4] = f2b(hi.x); pk.u[5] = f2b(hi.y); pk.u[6] = f2b(hi.z); pk.u[7] = f2b(hi.w);
            a = pk.v;
        }
#pragma unroll
        for (int nt = 0; nt < NTILES; ++nt) {
            bf16x8 b = *(const bf16x8*)(BT + (size_t)(nt * 16 + m) * K + k0);
            acc[nt] = __builtin_amdgcn_mfma_f32_16x16x32_bf16(a, b, acc[nt], 0, 0, 0);
        }
    }

#pragma unroll
    for (int reg = 0; reg < 4; ++reg) {
        const int r = r0 + kb * 4 + reg;
        if (r < M) {
            const float ds = dscale[r];
#pragma unroll
            for (int nt = 0; nt < NTILES; ++nt)
                C[(size_t)r * NF + nt * 16 + m] = f2b(acc[nt][reg] * ds);
        }
    }
}

// ---------------------------------------------------------------- fused aggregation (bf16 gather, fp32 accum)
template <int HF, bool FINAL>
__launch_bounds__(256)
__global__ void agg_kernel(const int* __restrict__ rowptr, const unsigned short* __restrict__ perm,
                           const unsigned short* __restrict__ xwb, const float* __restrict__ dinv,
                           const float* __restrict__ bias, const float* __restrict__ g,
                           const float* __restrict__ be, const float* __restrict__ m,
                           const float* __restrict__ v, const float* __restrict__ Wl,
                           const float* __restrict__ bl, void* __restrict__ outp) {
    constexpr int FPQ = HF / 32;
    const int wid = (blockIdx.x * blockDim.x + threadIdx.x) >> 6;
    if (wid >= N_NODES) return;
    const int lane = threadIdx.x & 63;
    const int half = lane >> 5;
    const int l5   = lane & 31;
    const int f0   = l5 * FPQ;
    const int d    = wid;

    float acc[FPQ];
#pragma unroll
    for (int q = 0; q < FPQ; ++q) acc[q] = 0.f;

    if (half == 0) {
        if constexpr (FPQ == 4) {
            uint2 t = *(const uint2*)(xwb + (size_t)d * HF + f0);
            add2(acc[0], acc[1], t.x);
            add2(acc[2], acc[3], t.y);
        } else {
            unsigned t = *(const unsigned*)(xwb + (size_t)d * HF + f0);
            add2(acc[0], acc[1], t);
        }
    }

    const int start = rowptr[d];
    const int end   = rowptr[d + 1];
    for (int base = start; base < end; base += 64) {
        int pidx = base + lane;
        int pv = perm[pidx < end ? pidx : end - 1];
        int ne = end - base;
        if (ne > 64) ne = 64;
        if (ne == 64) {
#pragma unroll
            for (int j = 0; j < 64; j += 2) {
                int s = __shfl(pv, j + half);
                if constexpr (FPQ == 4) {
                    uint2 t = *(const uint2*)(xwb + (size_t)s * HF + f0);
                    add2(acc[0], acc[1], t.x);
                    add2(acc[2], acc[3], t.y);
                } else {
                    unsigned t = *(const unsigned*)(xwb + (size_t)s * HF + f0);
                    add2(acc[0], acc[1], t);
                }
            }
        } else {
            for (int j = 0; j < ne; j += 2) {
                int s = __shfl(pv, j + half);
                if (j + half < ne) {
                    if constexpr (FPQ == 4) {
                        uint2 t = *(const uint2*)(xwb + (size_t)s * HF + f0);
                        add2(acc[0], acc[1], t.x);
                        add2(acc[2], acc[3], t.y);
                    } else {
                        unsigned t = *(const unsigned*)(xwb + (size_t)s * HF + f0);
                        add2(acc[0], acc[1], t);
                    }
                }
            }
        }
    }

#pragma unroll
    for (int q = 0; q < FPQ; ++q) acc[q] += __shfl_xor(acc[q], 32);

    const float dv = dinv[d];
    float y[FPQ];
#pragma unroll
    for (int q = 0; q < FPQ; ++q) {
        int f = f0 + q;
        float s  = g[f] * rsqrtf(v[f] + BN_EPS);
        float sh = (bias[f] - m[f]) * s + be[f];
        y[q] = fmaxf(acc[q] * dv * s + sh, 0.f);
    }

    if constexpr (!FINAL) {
        if (half == 0) {
            if constexpr (FPQ == 4) {
                ushort4 o;
                o.x = f2b(y[0]); o.y = f2b(y[1]); o.z = f2b(y[2]); o.w = f2b(y[3]);
                *(ushort4*)((unsigned short*)outp + (size_t)d * HF + f0) = o;
            }
        }
    } else {
        float p0 = y[0] * Wl[f0 * 2 + 0] + y[1] * Wl[(f0 + 1) * 2 + 0];
        float p1 = y[0] * Wl[f0 * 2 + 1] + y[1] * Wl[(f0 + 1) * 2 + 1];
#pragma unroll
        for (int off = 16; off > 0; off >>= 1) {
            p0 += __shfl_xor(p0, off);
            p1 += __shfl_xor(p1, off);
        }
        if (lane == 0) {
            float* o = (float*)outp;
            o[(size_t)d * 2 + 0] = p0 + bl[0];
            o[(size_t)d * 2 + 1] = p1 + bl[1];
        }
    }
}

// ---------------------------------------------------------------- launcher
extern "C" void kernel_launch(void* const* d_in, const int* in_sizes, int n_in,
                              void* d_out, int out_size, void* d_ws, size_t ws_size,
                              hipStream_t stream) {
    const float* x   = (const float*)d_in[0];
    const int*   ei  = (const int*)d_in[1];
    const float* W1  = (const float*)d_in[2];
    const float* b1  = (const float*)d_in[3];
    const float* g1  = (const float*)d_in[4];
    const float* be1 = (const float*)d_in[5];
    const float* m1  = (const float*)d_in[6];
    const float* v1  = (const float*)d_in[7];
    const float* W2  = (const float*)d_in[8];
    const float* b2  = (const float*)d_in[9];
    const float* g2  = (const float*)d_in[10];
    const float* be2 = (const float*)d_in[11];
    const float* m2  = (const float*)d_in[12];
    const float* v2  = (const float*)d_in[13];
    const float* Wl  = (const float*)d_in[14];
    const float* bl  = (const float*)d_in[15];

    const int* src = ei;            // edge_index[0]
    const int* dst = ei + N_EDGES;  // edge_index[1]

    // workspace layout (4B units; all chunks 16B-aligned)
    int*            h      = (int*)d_ws;                          // NCHUNK*NBUK
    int*            boff   = h + NCHUNK * NBUK;                   // 1024
    int*            rowptr = boff + 1024;                         // 50016
    float*          dinv   = (float*)(rowptr + 50016);            // 50016
    unsigned*       bedges = (unsigned*)(dinv + 50016);           // E
    unsigned short* perm   = (unsigned short*)(bedges + N_EDGES); // E ushorts
    unsigned short* xwb    = perm + N_EDGES;                      // N*128 bf16
    unsigned short* h1b    = xwb + (size_t)N_NODES * H1_F;        // N*128 bf16
    unsigned short* w1t    = h1b + (size_t)N_NODES * H1_F;        // 128*256 bf16
    unsigned short* w2t    = w1t + H1_F * IN_F;                   // 64*128 bf16

    // ---- CSR build (deterministic, no global returning atomics) ----
    chist_kernel<<<NCHUNK, 512, 0, stream>>>(dst, h);
    bscan2_kernel<<<1, 1024, 0, stream>>>(h, boff, rowptr);
    cscatter_kernel<<<NCHUNK, 512, 0, stream>>>(src, dst, h, bedges);
    build_kernel<<<NBUK, 256, 0, stream>>>(bedges, boff, perm, rowptr, dinv);

    // ---- weight transpose/convert ----
    wt_kernel<<<(H1_F * IN_F + 255) / 256, 256, 0, stream>>>(W1, w1t, IN_F, H1_F);
    wt_kernel<<<(H2_F * H1_F + 255) / 256, 256, 0, stream>>>(W2, w2t, H1_F, H2_F);

    // ---- layer 1 ----
    mfma_gemm_kernel<IN_F / 32, H1_F / 16, false><<<(N_NODES + 63) / 64, 256, 0, stream>>>(
        x, w1t, dinv, xwb, N_NODES);
    agg_kernel<H1_F, false><<<(N_NODES * 64) / 256, 256, 0, stream>>>(
        rowptr, perm, xwb, dinv, b1, g1, be1, m1, v1, nullptr, nullptr, h1b);

    // ---- layer 2 + final linear fused ----
    mfma_gemm_kernel<H1_F / 32, H2_F / 16, true><<<(N_NODES + 63) / 64, 256, 0, stream>>>(
        h1b, w2t, dinv, xwb, N_NODES);
    agg_kernel<H2_F, true><<<(N_NODES * 64) / 256, 256, 0, stream>>>(
        rowptr, perm, xwb, dinv, b2, g2, be2, m2, v2, Wl, bl, (float*)d_out);
}